// Round 7
// baseline (858.205 us; speedup 1.0000x reference)
//
#include <hip/hip_runtime.h>
#include <hip/hip_bf16.h>
#include <hip/hip_cooperative_groups.h>

namespace cg = cooperative_groups;

// GCN: out = relu(gcnconv(relu(gcnconv(x,W1,b1)), W2, b2)) @ Wfc + bfc
// N=50000, E=800000, F0=100, F1=256, F2=128. All-fp32 value path (bf16 blows
// the ~6e-6 relative threshold — round-4 post-mortem).
// Round 7: whole CSR build fused into ONE cooperative kernel (grid.sync
// between phases) — dispatch count 14 -> 5. Round-6 analysis: ~140 us of the
// 390 us total was inter-dispatch overhead (~10 us x 14 nodes); kernels
// themselves sum to ~250 us. Pulls/GEMMs unchanged from round 6.

#define F0 100
#define F1 256
#define F2 128

// ---------------- fused CSR construction (cooperative) ----------------
// phases: zero deg -> count deg -> per-chunk scan (+dinv) -> chunk-sum scan
// -> apply offsets (rowptr & cursor, rowptr[n]=e) -> fill csr.
__global__ __launch_bounds__(256) void csr_coop(
        const int* __restrict__ src, const int* __restrict__ dst,
        int* __restrict__ deg, int* __restrict__ bsum,
        int* __restrict__ rowptr, int* __restrict__ cursor,
        int* __restrict__ csr, float* __restrict__ dinv, int n, int e) {
    cg::grid_group grid = cg::this_grid();
    const int tid = threadIdx.x;
    const int gsz = gridDim.x * 256;
    const int gtid = blockIdx.x * 256 + tid;
    const int lane = tid & 63, wid = tid >> 6;
    __shared__ int wsum[4];

    // phase 0: zero degrees
    for (int i = gtid; i < n; i += gsz) deg[i] = 0;
    grid.sync();

    // phase 1: count in-degrees
    for (int i = gtid; i < e; i += gsz) atomicAdd(&deg[dst[i]], 1);
    grid.sync();

    // phase 2a: per-256-chunk exclusive scan (chunk-local) + dinv
    const int nb = (n + 255) / 256;  // 196
    for (int b = blockIdx.x; b < nb; b += gridDim.x) {
        int i = b * 256 + tid;
        int v = (i < n) ? deg[i] : 0;
        if (i < n) dinv[i] = rsqrtf((float)(v + 1));
        int s = v;
#pragma unroll
        for (int off = 1; off < 64; off <<= 1) {
            int t = __shfl_up(s, off, 64);
            if (lane >= off) s += t;
        }
        if (lane == 63) wsum[wid] = s;
        __syncthreads();
        int add = 0;
        for (int w = 0; w < wid; w++) add += wsum[w];
        if (i < n) rowptr[i] = add + s - v;  // chunk-local exclusive
        if (tid == 255) bsum[b] = add + s;   // chunk total
        __syncthreads();
    }
    grid.sync();

    // phase 2b: block 0 scans the chunk totals (nb <= 256) exclusively
    if (blockIdx.x == 0) {
        int v = (tid < nb) ? bsum[tid] : 0;
        int s = v;
#pragma unroll
        for (int off = 1; off < 64; off <<= 1) {
            int t = __shfl_up(s, off, 64);
            if (lane >= off) s += t;
        }
        if (lane == 63) wsum[wid] = s;
        __syncthreads();
        int add = 0;
        for (int w = 0; w < wid; w++) add += wsum[w];
        if (tid < nb) bsum[tid] = add + s - v;
    }
    grid.sync();

    // phase 2c: apply chunk offsets; write rowptr and cursor; rowptr[n]=e
    for (int i = gtid; i < n; i += gsz) {
        int r = rowptr[i] + bsum[i >> 8];
        rowptr[i] = r;
        cursor[i] = r;
    }
    if (gtid == 0) rowptr[n] = e;
    grid.sync();

    // phase 3: fill CSR (group edges by destination)
    for (int i = gtid; i < e; i += gsz) {
        int pos = atomicAdd(&cursor[dst[i]], 1);
        csr[pos] = src[i];
    }
}

// ---------------- pull-gather aggregation (fp32, high-MLP) ----------------

// aggX[v][:] = dinv[v]*( sum_{s in in(v)} dinv[s]*x[s][:] + dinv[v]*x[v][:] )
// One wave/node. Row = 400B = 25 float4. Lanes 0-24 even edges, 32-56 odd.
__global__ __launch_bounds__(256) void pull_f100(
        const float* __restrict__ x, const int* __restrict__ rowptr,
        const int* __restrict__ csr, const float* __restrict__ dinv,
        float* __restrict__ agg, int n) {
    int wave = threadIdx.x >> 6, lane = threadIdx.x & 63;
    int v = blockIdx.x * 4 + wave;
    if (v >= n) return;
    int beg = rowptr[v], end = rowptr[v + 1];
    float dv = dinv[v];
    int half = lane >> 5;
    int q = lane & 31;
    bool act = q < 25;
    float4 acc = {0.f, 0.f, 0.f, 0.f};

    for (int base = beg; base < end; base += 64) {
        int cnt = min(64, end - base);
        int sidx = (lane < cnt) ? csr[base + lane] : v;
        float scoef = (lane < cnt) ? dinv[sidx] : 0.f;
        int npairs = (cnt + 1) >> 1;
        int p = 0;
        for (; p + 4 <= npairs; p += 4) {
            int s0 = __shfl(sidx, 2 * p + half, 64);
            int s1 = __shfl(sidx, 2 * (p + 1) + half, 64);
            int s2 = __shfl(sidx, 2 * (p + 2) + half, 64);
            int s3 = __shfl(sidx, 2 * (p + 3) + half, 64);
            float c0 = __shfl(scoef, 2 * p + half, 64);
            float c1 = __shfl(scoef, 2 * (p + 1) + half, 64);
            float c2 = __shfl(scoef, 2 * (p + 2) + half, 64);
            float c3 = __shfl(scoef, 2 * (p + 3) + half, 64);
            if (act) {
                float4 r0 = ((const float4*)(x + (size_t)s0 * F0))[q];
                float4 r1 = ((const float4*)(x + (size_t)s1 * F0))[q];
                float4 r2 = ((const float4*)(x + (size_t)s2 * F0))[q];
                float4 r3 = ((const float4*)(x + (size_t)s3 * F0))[q];
                acc.x += c0 * r0.x + c1 * r1.x + c2 * r2.x + c3 * r3.x;
                acc.y += c0 * r0.y + c1 * r1.y + c2 * r2.y + c3 * r3.y;
                acc.z += c0 * r0.z + c1 * r1.z + c2 * r2.z + c3 * r3.z;
                acc.w += c0 * r0.w + c1 * r1.w + c2 * r2.w + c3 * r3.w;
            }
        }
        for (; p < npairs; p++) {
            int s0 = __shfl(sidx, 2 * p + half, 64);
            float c0 = __shfl(scoef, 2 * p + half, 64);
            if (act) {
                float4 r0 = ((const float4*)(x + (size_t)s0 * F0))[q];
                acc.x += c0 * r0.x;
                acc.y += c0 * r0.y;
                acc.z += c0 * r0.z;
                acc.w += c0 * r0.w;
            }
        }
    }
    float ox = __shfl_down(acc.x, 32, 64);
    float oy = __shfl_down(acc.y, 32, 64);
    float oz = __shfl_down(acc.z, 32, 64);
    float ow = __shfl_down(acc.w, 32, 64);
    if (half == 0 && act) {
        float4 hv = ((const float4*)(x + (size_t)v * F0))[q];
        float4 r;
        r.x = dv * (acc.x + ox + dv * hv.x);
        r.y = dv * (acc.y + oy + dv * hv.y);
        r.z = dv * (acc.z + oz + dv * hv.z);
        r.w = dv * (acc.w + ow + dv * hv.w);
        ((float4*)(agg + (size_t)v * F0))[q] = r;
    }
}

// Fused layer-2 aggregation + bias + relu + final FC. Row = 512B = 32 float4.
__global__ __launch_bounds__(256) void pull_f128_fused(
        const float* __restrict__ h2, const int* __restrict__ rowptr,
        const int* __restrict__ csr, const float* __restrict__ dinv,
        const float* __restrict__ b2, const float* __restrict__ Wfc,
        const float* __restrict__ bfc, float* __restrict__ out, int n) {
    int wave = threadIdx.x >> 6, lane = threadIdx.x & 63;
    int v = blockIdx.x * 4 + wave;
    if (v >= n) return;
    int beg = rowptr[v], end = rowptr[v + 1];
    float dv = dinv[v];
    int half = lane >> 5;
    int q = lane & 31;
    float4 acc = {0.f, 0.f, 0.f, 0.f};

    for (int base = beg; base < end; base += 64) {
        int cnt = min(64, end - base);
        int sidx = (lane < cnt) ? csr[base + lane] : v;
        float scoef = (lane < cnt) ? dinv[sidx] : 0.f;
        int npairs = (cnt + 1) >> 1;
        int p = 0;
        for (; p + 4 <= npairs; p += 4) {
            int s0 = __shfl(sidx, 2 * p + half, 64);
            int s1 = __shfl(sidx, 2 * (p + 1) + half, 64);
            int s2 = __shfl(sidx, 2 * (p + 2) + half, 64);
            int s3 = __shfl(sidx, 2 * (p + 3) + half, 64);
            float c0 = __shfl(scoef, 2 * p + half, 64);
            float c1 = __shfl(scoef, 2 * (p + 1) + half, 64);
            float c2 = __shfl(scoef, 2 * (p + 2) + half, 64);
            float c3 = __shfl(scoef, 2 * (p + 3) + half, 64);
            float4 r0 = ((const float4*)(h2 + (size_t)s0 * F2))[q];
            float4 r1 = ((const float4*)(h2 + (size_t)s1 * F2))[q];
            float4 r2 = ((const float4*)(h2 + (size_t)s2 * F2))[q];
            float4 r3 = ((const float4*)(h2 + (size_t)s3 * F2))[q];
            acc.x += c0 * r0.x + c1 * r1.x + c2 * r2.x + c3 * r3.x;
            acc.y += c0 * r0.y + c1 * r1.y + c2 * r2.y + c3 * r3.y;
            acc.z += c0 * r0.z + c1 * r1.z + c2 * r2.z + c3 * r3.z;
            acc.w += c0 * r0.w + c1 * r1.w + c2 * r2.w + c3 * r3.w;
        }
        for (; p < npairs; p++) {
            int s0 = __shfl(sidx, 2 * p + half, 64);
            float c0 = __shfl(scoef, 2 * p + half, 64);
            float4 r0 = ((const float4*)(h2 + (size_t)s0 * F2))[q];
            acc.x += c0 * r0.x;
            acc.y += c0 * r0.y;
            acc.z += c0 * r0.z;
            acc.w += c0 * r0.w;
        }
    }
    float ox = __shfl_down(acc.x, 32, 64);
    float oy = __shfl_down(acc.y, 32, 64);
    float oz = __shfl_down(acc.z, 32, 64);
    float ow = __shfl_down(acc.w, 32, 64);
    float part = 0.f;
    if (half == 0) {
        float4 hv = ((const float4*)(h2 + (size_t)v * F2))[q];
        float4 b2v = ((const float4*)b2)[q];
        float4 wv = ((const float4*)Wfc)[q];
        float t0 = dv * (acc.x + ox + dv * hv.x);
        float t1 = dv * (acc.y + oy + dv * hv.y);
        float t2 = dv * (acc.z + oz + dv * hv.z);
        float t3 = dv * (acc.w + ow + dv * hv.w);
        part = fmaxf(t0 + b2v.x, 0.f) * wv.x + fmaxf(t1 + b2v.y, 0.f) * wv.y +
               fmaxf(t2 + b2v.z, 0.f) * wv.z + fmaxf(t3 + b2v.w, 0.f) * wv.w;
        part += __shfl_down(part, 16, 64);
        part += __shfl_down(part, 8, 64);
        part += __shfl_down(part, 4, 64);
        part += __shfl_down(part, 2, 64);
        part += __shfl_down(part, 1, 64);
        if (lane == 0) out[v] = part + bfc[0];
    }
}

// ---------------- dense transforms (fp32, 128x128 tile, 8x8 micro) --------

// C = relu(A @ W + bias), A:[n,100], W:[100,256]. K chunked by 20.
__global__ __launch_bounds__(256) void gemm1_tiled(
        const float* __restrict__ A, const float* __restrict__ W,
        const float* __restrict__ bias, float* __restrict__ C, int n) {
    __shared__ float As[20 * 128];
    __shared__ float Bs[20 * 128];
    int tid = threadIdx.x;
    int r0 = blockIdx.x * 128;
    int c0 = blockIdx.y * 128;
    int tc = tid & 15, tr = tid >> 4;
    float acc[8][8] = {};

    for (int k0 = 0; k0 < F0; k0 += 20) {
        if (k0) __syncthreads();
        for (int idx = tid; idx < 128 * 5; idx += 256) {
            int row = idx & 127, kq = idx >> 7;
            int gr = r0 + row;
            if (gr >= n) gr = n - 1;
            float4 v = *(const float4*)(A + (size_t)gr * F0 + k0 + 4 * kq);
            As[(4 * kq + 0) * 128 + row] = v.x;
            As[(4 * kq + 1) * 128 + row] = v.y;
            As[(4 * kq + 2) * 128 + row] = v.z;
            As[(4 * kq + 3) * 128 + row] = v.w;
        }
        for (int idx = tid; idx < 20 * 32; idx += 256) {
            int k = idx >> 5, cq = idx & 31;
            *(float4*)(Bs + k * 128 + 4 * cq) =
                *(const float4*)(W + (size_t)(k0 + k) * F1 + c0 + 4 * cq);
        }
        __syncthreads();
#pragma unroll 5
        for (int k = 0; k < 20; k++) {
            float4 a0 = *(const float4*)(As + k * 128 + 4 * tr);
            float4 a1 = *(const float4*)(As + k * 128 + 64 + 4 * tr);
            float4 b0 = *(const float4*)(Bs + k * 128 + 4 * tc);
            float4 b1 = *(const float4*)(Bs + k * 128 + 64 + 4 * tc);
            float av[8] = {a0.x, a0.y, a0.z, a0.w, a1.x, a1.y, a1.z, a1.w};
            float bv[8] = {b0.x, b0.y, b0.z, b0.w, b1.x, b1.y, b1.z, b1.w};
#pragma unroll
            for (int i = 0; i < 8; i++)
#pragma unroll
                for (int j = 0; j < 8; j++) acc[i][j] += av[i] * bv[j];
        }
    }
    float4 bb0 = *(const float4*)(bias + c0 + 4 * tc);
    float4 bb1 = *(const float4*)(bias + c0 + 64 + 4 * tc);
    float bv[8] = {bb0.x, bb0.y, bb0.z, bb0.w, bb1.x, bb1.y, bb1.z, bb1.w};
#pragma unroll
    for (int i = 0; i < 8; i++) {
        int row = (i < 4) ? (4 * tr + i) : (64 + 4 * tr + i - 4);
        int gr = r0 + row;
        if (gr < n) {
            float4 o0, o1;
            o0.x = fmaxf(acc[i][0] + bv[0], 0.f);
            o0.y = fmaxf(acc[i][1] + bv[1], 0.f);
            o0.z = fmaxf(acc[i][2] + bv[2], 0.f);
            o0.w = fmaxf(acc[i][3] + bv[3], 0.f);
            o1.x = fmaxf(acc[i][4] + bv[4], 0.f);
            o1.y = fmaxf(acc[i][5] + bv[5], 0.f);
            o1.z = fmaxf(acc[i][6] + bv[6], 0.f);
            o1.w = fmaxf(acc[i][7] + bv[7], 0.f);
            *(float4*)(C + (size_t)gr * F1 + c0 + 4 * tc) = o0;
            *(float4*)(C + (size_t)gr * F1 + c0 + 64 + 4 * tc) = o1;
        }
    }
}

// C = A @ W, A:[n,256], W:[256,128]. Tile 128 rows x full F2, K by 32.
__global__ __launch_bounds__(256) void gemm2_tiled(
        const float* __restrict__ A, const float* __restrict__ W,
        float* __restrict__ C, int n) {
    __shared__ float As[32 * 128];
    __shared__ float Bs[32 * 128];
    int tid = threadIdx.x;
    int r0 = blockIdx.x * 128;
    int tc = tid & 15, tr = tid >> 4;
    float acc[8][8] = {};

    for (int k0 = 0; k0 < F1; k0 += 32) {
        if (k0) __syncthreads();
        for (int idx = tid; idx < 128 * 8; idx += 256) {
            int row = idx & 127, kq = idx >> 7;
            int gr = r0 + row;
            if (gr >= n) gr = n - 1;
            float4 v = *(const float4*)(A + (size_t)gr * F1 + k0 + 4 * kq);
            As[(4 * kq + 0) * 128 + row] = v.x;
            As[(4 * kq + 1) * 128 + row] = v.y;
            As[(4 * kq + 2) * 128 + row] = v.z;
            As[(4 * kq + 3) * 128 + row] = v.w;
        }
        for (int idx = tid; idx < 32 * 32; idx += 256) {
            int k = idx >> 5, cq = idx & 31;
            *(float4*)(Bs + k * 128 + 4 * cq) =
                *(const float4*)(W + (size_t)(k0 + k) * F2 + 4 * cq);
        }
        __syncthreads();
#pragma unroll 4
        for (int k = 0; k < 32; k++) {
            float4 a0 = *(const float4*)(As + k * 128 + 4 * tr);
            float4 a1 = *(const float4*)(As + k * 128 + 64 + 4 * tr);
            float4 b0 = *(const float4*)(Bs + k * 128 + 4 * tc);
            float4 b1 = *(const float4*)(Bs + k * 128 + 64 + 4 * tc);
            float av[8] = {a0.x, a0.y, a0.z, a0.w, a1.x, a1.y, a1.z, a1.w};
            float bv[8] = {b0.x, b0.y, b0.z, b0.w, b1.x, b1.y, b1.z, b1.w};
#pragma unroll
            for (int i = 0; i < 8; i++)
#pragma unroll
                for (int j = 0; j < 8; j++) acc[i][j] += av[i] * bv[j];
        }
    }
#pragma unroll
    for (int i = 0; i < 8; i++) {
        int row = (i < 4) ? (4 * tr + i) : (64 + 4 * tr + i - 4);
        int gr = r0 + row;
        if (gr < n) {
            float4 o0 = {acc[i][0], acc[i][1], acc[i][2], acc[i][3]};
            float4 o1 = {acc[i][4], acc[i][5], acc[i][6], acc[i][7]};
            *(float4*)(C + (size_t)gr * F2 + 4 * tc) = o0;
            *(float4*)(C + (size_t)gr * F2 + 64 + 4 * tc) = o1;
        }
    }
}

// ---------------- launch ----------------

static inline size_t align16(size_t x) { return (x + 3) & ~(size_t)3; }  // in 4B elems

extern "C" void kernel_launch(void* const* d_in, const int* in_sizes, int n_in,
                              void* d_out, int out_size, void* d_ws, size_t ws_size,
                              hipStream_t stream) {
    const float* x   = (const float*)d_in[0];
    const int*   ei  = (const int*)d_in[1];
    const float* W1  = (const float*)d_in[2];
    const float* b1  = (const float*)d_in[3];
    const float* W2  = (const float*)d_in[4];
    const float* b2  = (const float*)d_in[5];
    const float* Wfc = (const float*)d_in[6];
    const float* bfc = (const float*)d_in[7];
    float* out = (float*)d_out;

    int n = in_sizes[0] / F0;   // 50000
    int e = in_sizes[1] / 2;    // 800000
    const int* src = ei;
    const int* dst = ei + e;

    // workspace layout (4-byte elements, each region 16B-aligned)
    char* wsb = (char*)d_ws;
    size_t off = 0;
    int* deg    = (int*)(wsb + 4 * off); off = align16(off + n);
    int* bsum   = (int*)(wsb + 4 * off); off = align16(off + 256);
    int* rowptr = (int*)(wsb + 4 * off); off = align16(off + n + 1);
    int* cursor = (int*)(wsb + 4 * off); off = align16(off + n);
    int* csr    = (int*)(wsb + 4 * off); off = align16(off + e);
    float* dinv = (float*)(wsb + 4 * off); off = align16(off + n);
    float* aggX = (float*)(wsb + 4 * off); off = align16(off + (size_t)n * F0);
    float* a1   = (float*)(wsb + 4 * off); off = align16(off + (size_t)n * F1);
    float* h2   = (float*)(wsb + 4 * off); off = align16(off + (size_t)n * F2);

    const int rblocks = (n + 127) / 128;

    // fused CSR build: one cooperative dispatch
    {
        void* args[] = {(void*)&src, (void*)&dst, (void*)&deg, (void*)&bsum,
                        (void*)&rowptr, (void*)&cursor, (void*)&csr,
                        (void*)&dinv, (void*)&n, (void*)&e};
        hipLaunchCooperativeKernel((void*)csr_coop, dim3(1024), dim3(256),
                                   args, 0, stream);
    }

    // layer 1: pull-aggregate x (100-dim), then tiled GEMM + bias + relu
    pull_f100<<<(n + 3) / 4, 256, 0, stream>>>(x, rowptr, csr, dinv, aggX, n);
    gemm1_tiled<<<dim3(rblocks, F1 / 128), 256, 0, stream>>>(aggX, W1, b1, a1, n);

    // layer 2: tiled GEMM 256->128, then fused pull + bias + relu + FC
    gemm2_tiled<<<rblocks, 256, 0, stream>>>(a1, W2, h2, n);
    pull_f128_fused<<<(n + 3) / 4, 256, 0, stream>>>(h2, rowptr, csr, dinv,
                                                     b2, Wfc, bfc, out, n);
}

// Round 8
// 387.531 us; speedup vs baseline: 2.2145x; 2.2145x over previous
//
#include <hip/hip_runtime.h>
#include <hip/hip_bf16.h>

// GCN: out = relu(gcnconv(relu(gcnconv(x,W1,b1)), W2, b2)) @ Wfc + bfc
// N=50000, E=800000, F0=100, F1=256, F2=128. All-fp32 value path (bf16 blows
// the ~6e-6 relative threshold — round-4 post-mortem).
// Round 8: revert round-7 cooperative fusion (grid.sync costs ~110 us/sync on
// 8-XCD gfx950 — never use for us-scale phases). Round-6 structure with
// dispatch trims: make_dinv folded into scan1, cursor written by scan3
// (drops the memcpy node). 12 -> 10 graph nodes.

#define F0 100
#define F1 256
#define F2 128

// ---------------- CSR construction ----------------

__global__ void zero_i32(int* p, int n) {
    int i = blockIdx.x * blockDim.x + threadIdx.x;
    if (i < n) p[i] = 0;
}

__global__ void deg_count_i(const int* __restrict__ dst, int* deg, int e) {
    int i = blockIdx.x * blockDim.x + threadIdx.x;
    if (i < e) atomicAdd(deg + dst[i], 1);
}

// per-block exclusive scan of deg + block sums; also emits dinv = rsqrt(deg+1)
__global__ __launch_bounds__(256) void scan1(const int* __restrict__ deg,
                                             int* __restrict__ excl,
                                             int* __restrict__ bsum,
                                             float* __restrict__ dinv, int n) {
    __shared__ int wsum[4];
    int i = blockIdx.x * 256 + threadIdx.x;
    int lane = threadIdx.x & 63, wid = threadIdx.x >> 6;
    int v = (i < n) ? deg[i] : 0;
    if (i < n) dinv[i] = rsqrtf((float)(v + 1));
    int s = v;
#pragma unroll
    for (int off = 1; off < 64; off <<= 1) {
        int t = __shfl_up(s, off, 64);
        if (lane >= off) s += t;
    }
    if (lane == 63) wsum[wid] = s;
    __syncthreads();
    int add = 0;
    for (int w = 0; w < wid; w++) add += wsum[w];
    if (i < n) excl[i] = add + s - v;
    if (threadIdx.x == 255) bsum[blockIdx.x] = add + s;
}

__global__ __launch_bounds__(256) void scan2(int* __restrict__ bsum, int nb,
                                             int* __restrict__ rowptr, int n) {
    __shared__ int wsum[4];
    int lane = threadIdx.x & 63, wid = threadIdx.x >> 6;
    int v = (threadIdx.x < nb) ? bsum[threadIdx.x] : 0;
    int s = v;
#pragma unroll
    for (int off = 1; off < 64; off <<= 1) {
        int t = __shfl_up(s, off, 64);
        if (lane >= off) s += t;
    }
    if (lane == 63) wsum[wid] = s;
    __syncthreads();
    int add = 0;
    for (int w = 0; w < wid; w++) add += wsum[w];
    if (threadIdx.x < nb) bsum[threadIdx.x] = add + s - v;
    if (threadIdx.x == 255) rowptr[n] = add + s;
}

// apply block offsets; write both rowptr and cursor (csr_fill scratch)
__global__ void scan3(const int* __restrict__ excl, const int* __restrict__ bsum,
                      int* __restrict__ rowptr, int* __restrict__ cursor, int n) {
    int i = blockIdx.x * 256 + threadIdx.x;
    if (i < n) {
        int r = excl[i] + bsum[blockIdx.x];
        rowptr[i] = r;
        cursor[i] = r;
    }
}

__global__ void csr_fill(const int* __restrict__ src, const int* __restrict__ dst,
                         int* cursor, int* __restrict__ csr, int e) {
    int i = blockIdx.x * blockDim.x + threadIdx.x;
    if (i < e) {
        int pos = atomicAdd(cursor + dst[i], 1);
        csr[pos] = src[i];
    }
}

// ---------------- pull-gather aggregation (fp32, high-MLP) ----------------

// aggX[v][:] = dinv[v]*( sum_{s in in(v)} dinv[s]*x[s][:] + dinv[v]*x[v][:] )
// One wave/node. Row = 400B = 25 float4. Lanes 0-24 even edges, 32-56 odd.
__global__ __launch_bounds__(256) void pull_f100(
        const float* __restrict__ x, const int* __restrict__ rowptr,
        const int* __restrict__ csr, const float* __restrict__ dinv,
        float* __restrict__ agg, int n) {
    int wave = threadIdx.x >> 6, lane = threadIdx.x & 63;
    int v = blockIdx.x * 4 + wave;
    if (v >= n) return;
    int beg = rowptr[v], end = rowptr[v + 1];
    float dv = dinv[v];
    int half = lane >> 5;
    int q = lane & 31;
    bool act = q < 25;
    float4 acc = {0.f, 0.f, 0.f, 0.f};

    for (int base = beg; base < end; base += 64) {
        int cnt = min(64, end - base);
        int sidx = (lane < cnt) ? csr[base + lane] : v;
        float scoef = (lane < cnt) ? dinv[sidx] : 0.f;
        int npairs = (cnt + 1) >> 1;
        int p = 0;
        for (; p + 4 <= npairs; p += 4) {
            int s0 = __shfl(sidx, 2 * p + half, 64);
            int s1 = __shfl(sidx, 2 * (p + 1) + half, 64);
            int s2 = __shfl(sidx, 2 * (p + 2) + half, 64);
            int s3 = __shfl(sidx, 2 * (p + 3) + half, 64);
            float c0 = __shfl(scoef, 2 * p + half, 64);
            float c1 = __shfl(scoef, 2 * (p + 1) + half, 64);
            float c2 = __shfl(scoef, 2 * (p + 2) + half, 64);
            float c3 = __shfl(scoef, 2 * (p + 3) + half, 64);
            if (act) {
                float4 r0 = ((const float4*)(x + (size_t)s0 * F0))[q];
                float4 r1 = ((const float4*)(x + (size_t)s1 * F0))[q];
                float4 r2 = ((const float4*)(x + (size_t)s2 * F0))[q];
                float4 r3 = ((const float4*)(x + (size_t)s3 * F0))[q];
                acc.x += c0 * r0.x + c1 * r1.x + c2 * r2.x + c3 * r3.x;
                acc.y += c0 * r0.y + c1 * r1.y + c2 * r2.y + c3 * r3.y;
                acc.z += c0 * r0.z + c1 * r1.z + c2 * r2.z + c3 * r3.z;
                acc.w += c0 * r0.w + c1 * r1.w + c2 * r2.w + c3 * r3.w;
            }
        }
        for (; p < npairs; p++) {
            int s0 = __shfl(sidx, 2 * p + half, 64);
            float c0 = __shfl(scoef, 2 * p + half, 64);
            if (act) {
                float4 r0 = ((const float4*)(x + (size_t)s0 * F0))[q];
                acc.x += c0 * r0.x;
                acc.y += c0 * r0.y;
                acc.z += c0 * r0.z;
                acc.w += c0 * r0.w;
            }
        }
    }
    float ox = __shfl_down(acc.x, 32, 64);
    float oy = __shfl_down(acc.y, 32, 64);
    float oz = __shfl_down(acc.z, 32, 64);
    float ow = __shfl_down(acc.w, 32, 64);
    if (half == 0 && act) {
        float4 hv = ((const float4*)(x + (size_t)v * F0))[q];
        float4 r;
        r.x = dv * (acc.x + ox + dv * hv.x);
        r.y = dv * (acc.y + oy + dv * hv.y);
        r.z = dv * (acc.z + oz + dv * hv.z);
        r.w = dv * (acc.w + ow + dv * hv.w);
        ((float4*)(agg + (size_t)v * F0))[q] = r;
    }
}

// Fused layer-2 aggregation + bias + relu + final FC. Row = 512B = 32 float4.
__global__ __launch_bounds__(256) void pull_f128_fused(
        const float* __restrict__ h2, const int* __restrict__ rowptr,
        const int* __restrict__ csr, const float* __restrict__ dinv,
        const float* __restrict__ b2, const float* __restrict__ Wfc,
        const float* __restrict__ bfc, float* __restrict__ out, int n) {
    int wave = threadIdx.x >> 6, lane = threadIdx.x & 63;
    int v = blockIdx.x * 4 + wave;
    if (v >= n) return;
    int beg = rowptr[v], end = rowptr[v + 1];
    float dv = dinv[v];
    int half = lane >> 5;
    int q = lane & 31;
    float4 acc = {0.f, 0.f, 0.f, 0.f};

    for (int base = beg; base < end; base += 64) {
        int cnt = min(64, end - base);
        int sidx = (lane < cnt) ? csr[base + lane] : v;
        float scoef = (lane < cnt) ? dinv[sidx] : 0.f;
        int npairs = (cnt + 1) >> 1;
        int p = 0;
        for (; p + 4 <= npairs; p += 4) {
            int s0 = __shfl(sidx, 2 * p + half, 64);
            int s1 = __shfl(sidx, 2 * (p + 1) + half, 64);
            int s2 = __shfl(sidx, 2 * (p + 2) + half, 64);
            int s3 = __shfl(sidx, 2 * (p + 3) + half, 64);
            float c0 = __shfl(scoef, 2 * p + half, 64);
            float c1 = __shfl(scoef, 2 * (p + 1) + half, 64);
            float c2 = __shfl(scoef, 2 * (p + 2) + half, 64);
            float c3 = __shfl(scoef, 2 * (p + 3) + half, 64);
            float4 r0 = ((const float4*)(h2 + (size_t)s0 * F2))[q];
            float4 r1 = ((const float4*)(h2 + (size_t)s1 * F2))[q];
            float4 r2 = ((const float4*)(h2 + (size_t)s2 * F2))[q];
            float4 r3 = ((const float4*)(h2 + (size_t)s3 * F2))[q];
            acc.x += c0 * r0.x + c1 * r1.x + c2 * r2.x + c3 * r3.x;
            acc.y += c0 * r0.y + c1 * r1.y + c2 * r2.y + c3 * r3.y;
            acc.z += c0 * r0.z + c1 * r1.z + c2 * r2.z + c3 * r3.z;
            acc.w += c0 * r0.w + c1 * r1.w + c2 * r2.w + c3 * r3.w;
        }
        for (; p < npairs; p++) {
            int s0 = __shfl(sidx, 2 * p + half, 64);
            float c0 = __shfl(scoef, 2 * p + half, 64);
            float4 r0 = ((const float4*)(h2 + (size_t)s0 * F2))[q];
            acc.x += c0 * r0.x;
            acc.y += c0 * r0.y;
            acc.z += c0 * r0.z;
            acc.w += c0 * r0.w;
        }
    }
    float ox = __shfl_down(acc.x, 32, 64);
    float oy = __shfl_down(acc.y, 32, 64);
    float oz = __shfl_down(acc.z, 32, 64);
    float ow = __shfl_down(acc.w, 32, 64);
    float part = 0.f;
    if (half == 0) {
        float4 hv = ((const float4*)(h2 + (size_t)v * F2))[q];
        float4 b2v = ((const float4*)b2)[q];
        float4 wv = ((const float4*)Wfc)[q];
        float t0 = dv * (acc.x + ox + dv * hv.x);
        float t1 = dv * (acc.y + oy + dv * hv.y);
        float t2 = dv * (acc.z + oz + dv * hv.z);
        float t3 = dv * (acc.w + ow + dv * hv.w);
        part = fmaxf(t0 + b2v.x, 0.f) * wv.x + fmaxf(t1 + b2v.y, 0.f) * wv.y +
               fmaxf(t2 + b2v.z, 0.f) * wv.z + fmaxf(t3 + b2v.w, 0.f) * wv.w;
        part += __shfl_down(part, 16, 64);
        part += __shfl_down(part, 8, 64);
        part += __shfl_down(part, 4, 64);
        part += __shfl_down(part, 2, 64);
        part += __shfl_down(part, 1, 64);
        if (lane == 0) out[v] = part + bfc[0];
    }
}

// ---------------- dense transforms (fp32, 128x128 tile, 8x8 micro) --------

// C = relu(A @ W + bias), A:[n,100], W:[100,256]. K chunked by 20.
__global__ __launch_bounds__(256) void gemm1_tiled(
        const float* __restrict__ A, const float* __restrict__ W,
        const float* __restrict__ bias, float* __restrict__ C, int n) {
    __shared__ float As[20 * 128];
    __shared__ float Bs[20 * 128];
    int tid = threadIdx.x;
    int r0 = blockIdx.x * 128;
    int c0 = blockIdx.y * 128;
    int tc = tid & 15, tr = tid >> 4;
    float acc[8][8] = {};

    for (int k0 = 0; k0 < F0; k0 += 20) {
        if (k0) __syncthreads();
        for (int idx = tid; idx < 128 * 5; idx += 256) {
            int row = idx & 127, kq = idx >> 7;
            int gr = r0 + row;
            if (gr >= n) gr = n - 1;
            float4 v = *(const float4*)(A + (size_t)gr * F0 + k0 + 4 * kq);
            As[(4 * kq + 0) * 128 + row] = v.x;
            As[(4 * kq + 1) * 128 + row] = v.y;
            As[(4 * kq + 2) * 128 + row] = v.z;
            As[(4 * kq + 3) * 128 + row] = v.w;
        }
        for (int idx = tid; idx < 20 * 32; idx += 256) {
            int k = idx >> 5, cq = idx & 31;
            *(float4*)(Bs + k * 128 + 4 * cq) =
                *(const float4*)(W + (size_t)(k0 + k) * F1 + c0 + 4 * cq);
        }
        __syncthreads();
#pragma unroll 5
        for (int k = 0; k < 20; k++) {
            float4 a0 = *(const float4*)(As + k * 128 + 4 * tr);
            float4 a1 = *(const float4*)(As + k * 128 + 64 + 4 * tr);
            float4 b0 = *(const float4*)(Bs + k * 128 + 4 * tc);
            float4 b1 = *(const float4*)(Bs + k * 128 + 64 + 4 * tc);
            float av[8] = {a0.x, a0.y, a0.z, a0.w, a1.x, a1.y, a1.z, a1.w};
            float bv[8] = {b0.x, b0.y, b0.z, b0.w, b1.x, b1.y, b1.z, b1.w};
#pragma unroll
            for (int i = 0; i < 8; i++)
#pragma unroll
                for (int j = 0; j < 8; j++) acc[i][j] += av[i] * bv[j];
        }
    }
    float4 bb0 = *(const float4*)(bias + c0 + 4 * tc);
    float4 bb1 = *(const float4*)(bias + c0 + 64 + 4 * tc);
    float bv[8] = {bb0.x, bb0.y, bb0.z, bb0.w, bb1.x, bb1.y, bb1.z, bb1.w};
#pragma unroll
    for (int i = 0; i < 8; i++) {
        int row = (i < 4) ? (4 * tr + i) : (64 + 4 * tr + i - 4);
        int gr = r0 + row;
        if (gr < n) {
            float4 o0, o1;
            o0.x = fmaxf(acc[i][0] + bv[0], 0.f);
            o0.y = fmaxf(acc[i][1] + bv[1], 0.f);
            o0.z = fmaxf(acc[i][2] + bv[2], 0.f);
            o0.w = fmaxf(acc[i][3] + bv[3], 0.f);
            o1.x = fmaxf(acc[i][4] + bv[4], 0.f);
            o1.y = fmaxf(acc[i][5] + bv[5], 0.f);
            o1.z = fmaxf(acc[i][6] + bv[6], 0.f);
            o1.w = fmaxf(acc[i][7] + bv[7], 0.f);
            *(float4*)(C + (size_t)gr * F1 + c0 + 4 * tc) = o0;
            *(float4*)(C + (size_t)gr * F1 + c0 + 64 + 4 * tc) = o1;
        }
    }
}

// C = A @ W, A:[n,256], W:[256,128]. Tile 128 rows x full F2, K by 32.
__global__ __launch_bounds__(256) void gemm2_tiled(
        const float* __restrict__ A, const float* __restrict__ W,
        float* __restrict__ C, int n) {
    __shared__ float As[32 * 128];
    __shared__ float Bs[32 * 128];
    int tid = threadIdx.x;
    int r0 = blockIdx.x * 128;
    int tc = tid & 15, tr = tid >> 4;
    float acc[8][8] = {};

    for (int k0 = 0; k0 < F1; k0 += 32) {
        if (k0) __syncthreads();
        for (int idx = tid; idx < 128 * 8; idx += 256) {
            int row = idx & 127, kq = idx >> 7;
            int gr = r0 + row;
            if (gr >= n) gr = n - 1;
            float4 v = *(const float4*)(A + (size_t)gr * F1 + k0 + 4 * kq);
            As[(4 * kq + 0) * 128 + row] = v.x;
            As[(4 * kq + 1) * 128 + row] = v.y;
            As[(4 * kq + 2) * 128 + row] = v.z;
            As[(4 * kq + 3) * 128 + row] = v.w;
        }
        for (int idx = tid; idx < 32 * 32; idx += 256) {
            int k = idx >> 5, cq = idx & 31;
            *(float4*)(Bs + k * 128 + 4 * cq) =
                *(const float4*)(W + (size_t)(k0 + k) * F2 + 4 * cq);
        }
        __syncthreads();
#pragma unroll 4
        for (int k = 0; k < 32; k++) {
            float4 a0 = *(const float4*)(As + k * 128 + 4 * tr);
            float4 a1 = *(const float4*)(As + k * 128 + 64 + 4 * tr);
            float4 b0 = *(const float4*)(Bs + k * 128 + 4 * tc);
            float4 b1 = *(const float4*)(Bs + k * 128 + 64 + 4 * tc);
            float av[8] = {a0.x, a0.y, a0.z, a0.w, a1.x, a1.y, a1.z, a1.w};
            float bv[8] = {b0.x, b0.y, b0.z, b0.w, b1.x, b1.y, b1.z, b1.w};
#pragma unroll
            for (int i = 0; i < 8; i++)
#pragma unroll
                for (int j = 0; j < 8; j++) acc[i][j] += av[i] * bv[j];
        }
    }
#pragma unroll
    for (int i = 0; i < 8; i++) {
        int row = (i < 4) ? (4 * tr + i) : (64 + 4 * tr + i - 4);
        int gr = r0 + row;
        if (gr < n) {
            float4 o0 = {acc[i][0], acc[i][1], acc[i][2], acc[i][3]};
            float4 o1 = {acc[i][4], acc[i][5], acc[i][6], acc[i][7]};
            *(float4*)(C + (size_t)gr * F2 + 4 * tc) = o0;
            *(float4*)(C + (size_t)gr * F2 + 64 + 4 * tc) = o1;
        }
    }
}

// ---------------- launch ----------------

static inline size_t align16(size_t x) { return (x + 3) & ~(size_t)3; }  // in 4B elems

extern "C" void kernel_launch(void* const* d_in, const int* in_sizes, int n_in,
                              void* d_out, int out_size, void* d_ws, size_t ws_size,
                              hipStream_t stream) {
    const float* x   = (const float*)d_in[0];
    const int*   ei  = (const int*)d_in[1];
    const float* W1  = (const float*)d_in[2];
    const float* b1  = (const float*)d_in[3];
    const float* W2  = (const float*)d_in[4];
    const float* b2  = (const float*)d_in[5];
    const float* Wfc = (const float*)d_in[6];
    const float* bfc = (const float*)d_in[7];
    float* out = (float*)d_out;

    const int n = in_sizes[0] / F0;   // 50000
    const int e = in_sizes[1] / 2;    // 800000
    const int* src = ei;
    const int* dst = ei + e;

    // workspace layout (4-byte elements, each region 16B-aligned)
    char* wsb = (char*)d_ws;
    size_t off = 0;
    int* deg    = (int*)(wsb + 4 * off); off = align16(off + n);
    int* excl   = (int*)(wsb + 4 * off); off = align16(off + n);
    int* bsum   = (int*)(wsb + 4 * off); off = align16(off + 256);
    int* rowptr = (int*)(wsb + 4 * off); off = align16(off + n + 1);
    int* cursor = (int*)(wsb + 4 * off); off = align16(off + n);
    int* csr    = (int*)(wsb + 4 * off); off = align16(off + e);
    float* dinv = (float*)(wsb + 4 * off); off = align16(off + n);
    float* aggX = (float*)(wsb + 4 * off); off = align16(off + (size_t)n * F0);
    float* a1   = (float*)(wsb + 4 * off); off = align16(off + (size_t)n * F1);
    float* h2   = (float*)(wsb + 4 * off); off = align16(off + (size_t)n * F2);

    const int B = 256;
    const int nb = (n + B - 1) / B;          // 196 (<= 256)
    const int rblocks = (n + 127) / 128;

    // CSR build (6 dispatches, no cooperative launch)
    zero_i32<<<nb, B, 0, stream>>>(deg, n);
    deg_count_i<<<(e + B - 1) / B, B, 0, stream>>>(dst, deg, e);
    scan1<<<nb, B, 0, stream>>>(deg, excl, bsum, dinv, n);
    scan2<<<1, B, 0, stream>>>(bsum, nb, rowptr, n);
    scan3<<<nb, B, 0, stream>>>(excl, bsum, rowptr, cursor, n);
    csr_fill<<<(e + B - 1) / B, B, 0, stream>>>(src, dst, cursor, csr, e);

    // layer 1: pull-aggregate x (100-dim), then tiled GEMM + bias + relu
    pull_f100<<<(n + 3) / 4, 256, 0, stream>>>(x, rowptr, csr, dinv, aggX, n);
    gemm1_tiled<<<dim3(rblocks, F1 / 128), 256, 0, stream>>>(aggX, W1, b1, a1, n);

    // layer 2: tiled GEMM 256->128, then fused pull + bias + relu + FC
    gemm2_tiled<<<rblocks, 256, 0, stream>>>(a1, W2, h2, n);
    pull_f128_fused<<<(n + 3) / 4, 256, 0, stream>>>(h2, rowptr, csr, dinv,
                                                     b2, Wfc, bfc, out, n);
}